// Round 8
// baseline (108.288 us; speedup 1.0000x reference)
//
#include <hip/hip_runtime.h>
#include <hip/hip_bf16.h>

// CrossSigmoidFocalLoss: mean over (N,C) of focal_w * bce * row_w * cross_mask
// Folded per-element form (y = (c==t) ? -x : x):
//   term = (c==t ? 0.25 : 0.75) * sigmoid(y)^2 * softplus(y) * mask
//   mask = row_w(weight>0) * (t==C ? bit_c(int(weight)) : 1)
// weight < 2^16 so schema bits for c >= 16 are zero (c >= 32 handled explicitly).
// softplus(y) = max(y,0) + ln(1+e), e = exp(-|y|) = exp(-|x|); ln(1+e) via A&S 4.1.44.
//
// Single kernel: per-block partials + last-block finalizer (fixed-order reduce ->
// bitwise deterministic). Counter zeroed per launch by a 4B hipMemsetAsync.

#define NCLS 80
#define C4   (NCLS / 4)   // 20 float4 per row
#define NBLOCKS 2048
#define NTHREADS 256
#define STRIDE (NBLOCKS * NTHREADS)   // 524288 threads

typedef float f32x4 __attribute__((ext_vector_type(4)));

// ln(1+x) on [0,1], Abramowitz & Stegun 4.1.44 (|eps| <= 3e-8); sum(a_i)=ln2 exactly.
__device__ __forceinline__ float log1p_poly(float x) {
    float p = -0.0064535442f;
    p = __builtin_fmaf(p, x,  0.0360884937f);
    p = __builtin_fmaf(p, x, -0.0953293897f);
    p = __builtin_fmaf(p, x,  0.1676540711f);
    p = __builtin_fmaf(p, x, -0.2407338084f);
    p = __builtin_fmaf(p, x,  0.3317990258f);
    p = __builtin_fmaf(p, x, -0.4998741238f);
    p = __builtin_fmaf(p, x,  0.9999964239f);
    return p * x;
}

__device__ __forceinline__ float elem_term(float x, int c, int t, int wi, bool neg) {
    const bool  pos = (c == t);
    const int   bit = (c < 32) ? ((wi >> c) & 1) : 0;   // schema bit (0 for c>=16 anyway)
    const float m   = neg ? (float)bit : 1.0f;
    const float a   = pos ? 0.25f : 0.75f;
    const float y   = pos ? -x : x;
    const float e   = __expf(-fabsf(x));                 // v_exp_f32, e in (0,1]
    const float inv = __builtin_amdgcn_rcpf(1.0f + e);   // v_rcp_f32
    const float s   = (y >= 0.0f) ? inv : e * inv;       // sigmoid(y)
    const float sp  = fmaxf(y, 0.0f) + log1p_poly(e);    // softplus(y), stable
    return (a * m) * (s * s) * sp;
}

__device__ __forceinline__ float body(const float* __restrict__ pred,
                                      const int*   __restrict__ targets,
                                      const float* __restrict__ weight,
                                      int i) {
    const int n  = i / C4;              // magic-mul divide by 20
    const int r  = i - n * C4;
    const int c0 = r * 4;

    // pred is stream-once: nontemporal (nt) load, don't pollute L2/L3
    const f32x4 x4 = __builtin_nontemporal_load(reinterpret_cast<const f32x4*>(pred) + i);
    const int    t  = targets[n];
    const float  wf = weight[n];
    const int    wi = (int)wf;
    const bool  neg = (t == NCLS);
    const float  rw = (wf > 0.0f) ? 1.0f : 0.0f;

    const float s4 = elem_term(x4[0], c0 + 0, t, wi, neg)
                   + elem_term(x4[1], c0 + 1, t, wi, neg)
                   + elem_term(x4[2], c0 + 2, t, wi, neg)
                   + elem_term(x4[3], c0 + 3, t, wi, neg);
    return rw * s4;
}

template<int KITERS>
__global__ void __launch_bounds__(NTHREADS)
cfs_fused(const float* __restrict__ pred,
          const int*   __restrict__ targets,
          const float* __restrict__ weight,
          float* __restrict__ partials,
          unsigned* __restrict__ counter,
          float* __restrict__ out,
          int total4, float scale) {
    const int tid = blockIdx.x * NTHREADS + threadIdx.x;

    float acc = 0.0f;
    if constexpr (KITERS > 0) {
        #pragma unroll
        for (int k = 0; k < KITERS; ++k)
            acc += body(pred, targets, weight, tid + k * STRIDE);
    } else {
        for (int i = tid; i < total4; i += STRIDE)
            acc += body(pred, targets, weight, i);
    }

    // wave (64-lane) reduction
    #pragma unroll
    for (int off = 32; off > 0; off >>= 1)
        acc += __shfl_down(acc, off, 64);

    __shared__ float smem[NTHREADS / 64];
    __shared__ int lastFlag;
    const int lane = threadIdx.x & 63;
    const int wid  = threadIdx.x >> 6;
    if (lane == 0) smem[wid] = acc;
    __syncthreads();

    if (threadIdx.x == 0) {
        float v = 0.0f;
        #pragma unroll
        for (int w = 0; w < NTHREADS / 64; ++w) v += smem[w];
        // publish partial, fence (device scope), then bump the arrival counter
        __hip_atomic_store(&partials[blockIdx.x], v, __ATOMIC_RELAXED, __HIP_MEMORY_SCOPE_AGENT);
        __threadfence();
        const unsigned ret = __hip_atomic_fetch_add(counter, 1u, __ATOMIC_RELAXED,
                                                    __HIP_MEMORY_SCOPE_AGENT);
        lastFlag = (ret == NBLOCKS - 1);
    }
    __syncthreads();   // after this, smem is reusable

    if (lastFlag) {
        __threadfence();   // acquire side: observe all published partials
        // fixed-order read of all partials -> bitwise deterministic result
        float a2 = 0.0f;
        for (int i = threadIdx.x; i < NBLOCKS; i += NTHREADS)
            a2 += __hip_atomic_load(&partials[i], __ATOMIC_RELAXED, __HIP_MEMORY_SCOPE_AGENT);
        #pragma unroll
        for (int off = 32; off > 0; off >>= 1)
            a2 += __shfl_down(a2, off, 64);
        if (lane == 0) smem[wid] = a2;
        __syncthreads();
        if (threadIdx.x == 0) {
            float v = 0.0f;
            #pragma unroll
            for (int w = 0; w < NTHREADS / 64; ++w) v += smem[w];
            out[0] = v * scale;
        }
    }
}

extern "C" void kernel_launch(void* const* d_in, const int* in_sizes, int n_in,
                              void* d_out, int out_size, void* d_ws, size_t ws_size,
                              hipStream_t stream) {
    const float* pred     = (const float*)d_in[0];
    const int*   targets  = (const int*)  d_in[1];
    const float* weight   = (const float*)d_in[2];
    float*       out      = (float*)d_out;
    float*       partials = (float*)d_ws;                  // NBLOCKS floats
    unsigned*    counter  = (unsigned*)((char*)d_ws + NBLOCKS * sizeof(float));

    const int n_rows = in_sizes[1];          // 262144
    const int total4 = n_rows * C4;          // 5,242,880
    const float inv_total = 1.0f / (float)(n_rows * NCLS);

    (void)hipMemsetAsync(counter, 0, sizeof(unsigned), stream);  // arrival counter = 0

    if (total4 == 10 * STRIDE) {
        cfs_fused<10><<<NBLOCKS, NTHREADS, 0, stream>>>(pred, targets, weight,
                                                        partials, counter, out,
                                                        total4, inv_total);
    } else {
        cfs_fused<0><<<NBLOCKS, NTHREADS, 0, stream>>>(pred, targets, weight,
                                                       partials, counter, out,
                                                       total4, inv_total);
    }
}

// Round 9
// 41.994 us; speedup vs baseline: 2.5787x; 2.5787x over previous
//
#include <hip/hip_runtime.h>
#include <hip/hip_bf16.h>

// CrossSigmoidFocalLoss: mean over (N,C) of focal_w * bce * row_w * cross_mask
// Folded per-element form (y = (c==t) ? -x : x):
//   term = (c==t ? 0.25 : 0.75) * sigmoid(y)^2 * softplus(y) * mask
//   mask = row_w(weight>0) * (t==C ? bit_c(int(weight)) : 1)
// weight < 2^16 so schema bits for c >= 16 are zero (c >= 32 handled explicitly).
// softplus(y) = max(y,0) + ln(1+e), e = exp(-|x|); ln(1+e) via A&S 4.1.44 poly.
//
// Single kernel, last-block finalizer. Cross-XCD ordering WITHOUT __threadfence():
// partial stores are agent-scope atomics (sc1 -> write-through to the coherent
// LLC, past the non-coherent per-XCD L2); s_waitcnt vmcnt(0) guarantees the
// store reached the coherent point before the arrival-counter bump; finalizer
// reads partials with agent-scope atomic loads (sc1 -> bypass stale L2s).
// R8 lesson: __threadfence() per block = 2048 L2 writebacks = +80us.

#define NCLS 80
#define C4   (NCLS / 4)   // 20 float4 per row
#define NBLOCKS 2048
#define NTHREADS 256
#define STRIDE (NBLOCKS * NTHREADS)   // 524288 threads

typedef float f32x4 __attribute__((ext_vector_type(4)));

// ln(1+x) on [0,1], Abramowitz & Stegun 4.1.44 (|eps| <= 3e-8); sum(a_i)=ln2 exactly.
__device__ __forceinline__ float log1p_poly(float x) {
    float p = -0.0064535442f;
    p = __builtin_fmaf(p, x,  0.0360884937f);
    p = __builtin_fmaf(p, x, -0.0953293897f);
    p = __builtin_fmaf(p, x,  0.1676540711f);
    p = __builtin_fmaf(p, x, -0.2407338084f);
    p = __builtin_fmaf(p, x,  0.3317990258f);
    p = __builtin_fmaf(p, x, -0.4998741238f);
    p = __builtin_fmaf(p, x,  0.9999964239f);
    return p * x;
}

__device__ __forceinline__ float elem_term(float x, int c, int t, int wi, bool neg) {
    const bool  pos = (c == t);
    const int   bit = (c < 32) ? ((wi >> c) & 1) : 0;   // schema bit (0 for c>=16 anyway)
    const float m   = neg ? (float)bit : 1.0f;
    const float a   = pos ? 0.25f : 0.75f;
    const float y   = pos ? -x : x;
    const float e   = __expf(-fabsf(x));                 // v_exp_f32, e in (0,1]
    const float inv = __builtin_amdgcn_rcpf(1.0f + e);   // v_rcp_f32
    const float s   = (y >= 0.0f) ? inv : e * inv;       // sigmoid(y)
    const float sp  = fmaxf(y, 0.0f) + log1p_poly(e);    // softplus(y), stable
    return (a * m) * (s * s) * sp;
}

template<int KITERS>
__global__ void __launch_bounds__(NTHREADS)
cfs_fused(const float* __restrict__ pred,
          const int*   __restrict__ targets,
          const float* __restrict__ weight,
          float* __restrict__ partials,
          unsigned* __restrict__ counter,
          float* __restrict__ out,
          int total4, float scale) {
    const int tid = blockIdx.x * NTHREADS + threadIdx.x;

    float acc = 0.0f;
    if constexpr (KITERS > 0) {
        // Stage ALL loads first (statically indexed after unroll -> registers,
        // all in flight), then compute. Forces pipelined HBM reads.
        f32x4 x[KITERS];
        int   tt[KITERS];
        float wf[KITERS];
        #pragma unroll
        for (int k = 0; k < KITERS; ++k) {
            const int i = tid + k * STRIDE;
            const int n = i / C4;
            x[k]  = __builtin_nontemporal_load(reinterpret_cast<const f32x4*>(pred) + i);
            tt[k] = targets[n];
            wf[k] = weight[n];
        }
        #pragma unroll
        for (int k = 0; k < KITERS; ++k) {
            const int i  = tid + k * STRIDE;
            const int n  = i / C4;              // magic-mul divide by 20
            const int c0 = (i - n * C4) * 4;
            const int   t   = tt[k];
            const float w   = wf[k];
            const int   wi  = (int)w;
            const bool  neg = (t == NCLS);
            const float rw  = (w > 0.0f) ? 1.0f : 0.0f;
            const float s4 = elem_term(x[k][0], c0 + 0, t, wi, neg)
                           + elem_term(x[k][1], c0 + 1, t, wi, neg)
                           + elem_term(x[k][2], c0 + 2, t, wi, neg)
                           + elem_term(x[k][3], c0 + 3, t, wi, neg);
            acc = __builtin_fmaf(rw, s4, acc);
        }
    } else {
        for (int i = tid; i < total4; i += STRIDE) {
            const int n  = i / C4;
            const int c0 = (i - n * C4) * 4;
            const f32x4 x4 = __builtin_nontemporal_load(reinterpret_cast<const f32x4*>(pred) + i);
            const int   t   = targets[n];
            const float w   = weight[n];
            const int   wi  = (int)w;
            const bool  neg = (t == NCLS);
            const float rw  = (w > 0.0f) ? 1.0f : 0.0f;
            const float s4 = elem_term(x4[0], c0 + 0, t, wi, neg)
                           + elem_term(x4[1], c0 + 1, t, wi, neg)
                           + elem_term(x4[2], c0 + 2, t, wi, neg)
                           + elem_term(x4[3], c0 + 3, t, wi, neg);
            acc = __builtin_fmaf(rw, s4, acc);
        }
    }

    // wave (64-lane) reduction
    #pragma unroll
    for (int off = 32; off > 0; off >>= 1)
        acc += __shfl_down(acc, off, 64);

    __shared__ float smem[NTHREADS / 64];
    __shared__ int lastFlag;
    const int lane = threadIdx.x & 63;
    const int wid  = threadIdx.x >> 6;
    if (lane == 0) smem[wid] = acc;
    __syncthreads();

    if (threadIdx.x == 0) {
        const float v = smem[0] + smem[1] + smem[2] + smem[3];
        // agent-scope atomic store: sc1, write-through to coherent LLC
        __hip_atomic_store(&partials[blockIdx.x], v, __ATOMIC_RELAXED, __HIP_MEMORY_SCOPE_AGENT);
        // completion (not cache-writeback!) ordering before the counter bump
        asm volatile("s_waitcnt vmcnt(0)" ::: "memory");
        const unsigned ret = __hip_atomic_fetch_add(counter, 1u, __ATOMIC_RELAXED,
                                                    __HIP_MEMORY_SCOPE_AGENT);
        lastFlag = (ret == NBLOCKS - 1);
    }
    __syncthreads();   // after this, smem is reusable

    if (lastFlag) {
        // fixed-order read of all partials (agent-scope loads bypass stale L2)
        float a2 = 0.0f;
        for (int i = threadIdx.x; i < NBLOCKS; i += NTHREADS)
            a2 += __hip_atomic_load(&partials[i], __ATOMIC_RELAXED, __HIP_MEMORY_SCOPE_AGENT);
        #pragma unroll
        for (int off = 32; off > 0; off >>= 1)
            a2 += __shfl_down(a2, off, 64);
        if (lane == 0) smem[wid] = a2;
        __syncthreads();
        if (threadIdx.x == 0)
            out[0] = (smem[0] + smem[1] + smem[2] + smem[3]) * scale;
    }
}

extern "C" void kernel_launch(void* const* d_in, const int* in_sizes, int n_in,
                              void* d_out, int out_size, void* d_ws, size_t ws_size,
                              hipStream_t stream) {
    const float* pred     = (const float*)d_in[0];
    const int*   targets  = (const int*)  d_in[1];
    const float* weight   = (const float*)d_in[2];
    float*       out      = (float*)d_out;
    float*       partials = (float*)d_ws;                  // NBLOCKS floats
    unsigned*    counter  = (unsigned*)((char*)d_ws + NBLOCKS * sizeof(float));

    const int n_rows = in_sizes[1];          // 262144
    const int total4 = n_rows * C4;          // 5,242,880
    const float inv_total = 1.0f / (float)(n_rows * NCLS);

    (void)hipMemsetAsync(counter, 0, sizeof(unsigned), stream);  // arrival counter = 0

    if (total4 == 10 * STRIDE) {
        cfs_fused<10><<<NBLOCKS, NTHREADS, 0, stream>>>(pred, targets, weight,
                                                        partials, counter, out,
                                                        total4, inv_total);
    } else {
        cfs_fused<0><<<NBLOCKS, NTHREADS, 0, stream>>>(pred, targets, weight,
                                                       partials, counter, out,
                                                       total4, inv_total);
    }
}

// Round 11
// 27.425 us; speedup vs baseline: 3.9486x; 1.5312x over previous
//
#include <hip/hip_runtime.h>
#include <hip/hip_bf16.h>

// CrossSigmoidFocalLoss: mean over (N,C) of focal_w * bce * row_w * cross_mask
// Folded per-element form (y = (c==t) ? -x : x):
//   term = (c==t ? 0.25 : 0.75) * sigmoid(y)^2 * softplus(y) * mask
//   mask = row_w(weight>0) * (t==C ? bit_c(int(weight)) : 1)
// weight < 2^16 so schema bits for c >= 16 are zero (c >= 32 handled explicitly).
// softplus(y) = max(y,0) + ln(1+e), e = exp(-|x|); ln(1+e) via A&S 4.1.44 poly.
//
// Structure: two kernels (per-block partials -> 1-block reduce). NO atomics,
// NO memset, NO fences. R8/R9 lessons: per-block __threadfence = 2048 L2
// writebacks (+66us); 2048 same-address arrival atomics = serialized LLC
// tail (~+10-30us). Plain stores + second kernel is cheaper than both.
// This round's single variable vs R5: explicit 10-deep load staging.

#define NCLS 80
#define C4   (NCLS / 4)   // 20 float4 per row
#define NBLOCKS 2048
#define NTHREADS 256
#define STRIDE (NBLOCKS * NTHREADS)   // 524288 threads

typedef float f32x4 __attribute__((ext_vector_type(4)));

// ln(1+x) on [0,1], Abramowitz & Stegun 4.1.44 (|eps| <= 3e-8); sum(a_i)=ln2 exactly.
__device__ __forceinline__ float log1p_poly(float x) {
    float p = -0.0064535442f;
    p = __builtin_fmaf(p, x,  0.0360884937f);
    p = __builtin_fmaf(p, x, -0.0953293897f);
    p = __builtin_fmaf(p, x,  0.1676540711f);
    p = __builtin_fmaf(p, x, -0.2407338084f);
    p = __builtin_fmaf(p, x,  0.3317990258f);
    p = __builtin_fmaf(p, x, -0.4998741238f);
    p = __builtin_fmaf(p, x,  0.9999964239f);
    return p * x;
}

__device__ __forceinline__ float elem_term(float x, int c, int t, int wi, bool neg) {
    const bool  pos = (c == t);
    const int   bit = (c < 32) ? ((wi >> c) & 1) : 0;   // schema bit (0 for c>=16 anyway)
    const float m   = neg ? (float)bit : 1.0f;
    const float a   = pos ? 0.25f : 0.75f;
    const float y   = pos ? -x : x;
    const float e   = __expf(-fabsf(x));                 // v_exp_f32, e in (0,1]
    const float inv = __builtin_amdgcn_rcpf(1.0f + e);   // v_rcp_f32
    const float s   = (y >= 0.0f) ? inv : e * inv;       // sigmoid(y)
    const float sp  = fmaxf(y, 0.0f) + log1p_poly(e);    // softplus(y), stable
    return (a * m) * (s * s) * sp;
}

template<int KITERS>
__global__ void __launch_bounds__(NTHREADS)
cfs_main(const float* __restrict__ pred,
         const int*   __restrict__ targets,
         const float* __restrict__ weight,
         float* __restrict__ partials,
         int total4) {
    const int tid = blockIdx.x * NTHREADS + threadIdx.x;

    float acc = 0.0f;
    if constexpr (KITERS > 0) {
        // Stage ALL loads first (statically indexed -> registers, all in
        // flight), then compute. ~70 VGPR of staged data, well under budget.
        f32x4 x[KITERS];
        int   tt[KITERS];
        float wf[KITERS];
        #pragma unroll
        for (int k = 0; k < KITERS; ++k) {
            const int i = tid + k * STRIDE;
            const int n = i / C4;
            x[k]  = reinterpret_cast<const f32x4*>(pred)[i];
            tt[k] = targets[n];
            wf[k] = weight[n];
        }
        #pragma unroll
        for (int k = 0; k < KITERS; ++k) {
            const int i  = tid + k * STRIDE;
            const int n  = i / C4;              // magic-mul divide by 20
            const int c0 = (i - n * C4) * 4;
            const int   t   = tt[k];
            const float w   = wf[k];
            const int   wi  = (int)w;
            const bool  neg = (t == NCLS);
            const float rw  = (w > 0.0f) ? 1.0f : 0.0f;
            const float s4 = elem_term(x[k][0], c0 + 0, t, wi, neg)
                           + elem_term(x[k][1], c0 + 1, t, wi, neg)
                           + elem_term(x[k][2], c0 + 2, t, wi, neg)
                           + elem_term(x[k][3], c0 + 3, t, wi, neg);
            acc = __builtin_fmaf(rw, s4, acc);
        }
    } else {
        for (int i = tid; i < total4; i += STRIDE) {
            const int n  = i / C4;
            const int c0 = (i - n * C4) * 4;
            const f32x4 x4 = reinterpret_cast<const f32x4*>(pred)[i];
            const int   t   = targets[n];
            const float w   = weight[n];
            const int   wi  = (int)w;
            const bool  neg = (t == NCLS);
            const float rw  = (w > 0.0f) ? 1.0f : 0.0f;
            const float s4 = elem_term(x4[0], c0 + 0, t, wi, neg)
                           + elem_term(x4[1], c0 + 1, t, wi, neg)
                           + elem_term(x4[2], c0 + 2, t, wi, neg)
                           + elem_term(x4[3], c0 + 3, t, wi, neg);
            acc = __builtin_fmaf(rw, s4, acc);
        }
    }

    // wave (64-lane) reduction
    #pragma unroll
    for (int off = 32; off > 0; off >>= 1)
        acc += __shfl_down(acc, off, 64);

    __shared__ float smem[NTHREADS / 64];
    const int lane = threadIdx.x & 63;
    const int wid  = threadIdx.x >> 6;
    if (lane == 0) smem[wid] = acc;
    __syncthreads();
    if (threadIdx.x == 0)
        partials[blockIdx.x] = smem[0] + smem[1] + smem[2] + smem[3];
}

__global__ void __launch_bounds__(NTHREADS)
cfs_reduce(const float* __restrict__ partials, float* __restrict__ out,
           int nparts, float scale) {
    float acc = 0.0f;
    for (int i = threadIdx.x; i < nparts; i += NTHREADS)
        acc += partials[i];
    #pragma unroll
    for (int off = 32; off > 0; off >>= 1)
        acc += __shfl_down(acc, off, 64);

    __shared__ float smem[NTHREADS / 64];
    const int lane = threadIdx.x & 63;
    const int wid  = threadIdx.x >> 6;
    if (lane == 0) smem[wid] = acc;
    __syncthreads();
    if (threadIdx.x == 0)
        out[0] = (smem[0] + smem[1] + smem[2] + smem[3]) * scale;
}

extern "C" void kernel_launch(void* const* d_in, const int* in_sizes, int n_in,
                              void* d_out, int out_size, void* d_ws, size_t ws_size,
                              hipStream_t stream) {
    const float* pred     = (const float*)d_in[0];
    const int*   targets  = (const int*)  d_in[1];
    const float* weight   = (const float*)d_in[2];
    float*       out      = (float*)d_out;
    float*       partials = (float*)d_ws;   // NBLOCKS floats of scratch

    const int n_rows = in_sizes[1];          // 262144
    const int total4 = n_rows * C4;          // 5,242,880
    const float inv_total = 1.0f / (float)(n_rows * NCLS);

    if (total4 == 10 * STRIDE) {
        cfs_main<10><<<NBLOCKS, NTHREADS, 0, stream>>>(pred, targets, weight, partials, total4);
    } else {
        cfs_main<0><<<NBLOCKS, NTHREADS, 0, stream>>>(pred, targets, weight, partials, total4);
    }
    cfs_reduce<<<1, NTHREADS, 0, stream>>>(partials, out, NBLOCKS, inv_total);
}

// Round 12
// 26.491 us; speedup vs baseline: 4.0877x; 1.0352x over previous
//
#include <hip/hip_runtime.h>
#include <hip/hip_bf16.h>

// CrossSigmoidFocalLoss: mean over (N,C) of focal_w * bce * row_w * cross_mask
// Folded per-element form (y = (c==t) ? -x : x):
//   term = (c==t ? 0.25 : 0.75) * sigmoid(y)^2 * softplus(y) * mask
//   mask = row_w(weight>0) * (t==C ? bit_c(int(weight)) : 1)
// weight < 2^16 so schema bits for c >= 16 are zero (c >= 32 handled explicitly).
// softplus(y) = max(y,0) + ln(1+e), e = exp(-|x|); ln(1+e) via A&S 4.1.44 poly.
//
// Structure: two kernels (per-block partials -> 1-block reduce); no atomics/fences
// (R8: per-block __threadfence = +66us; R9: same-address arrival atomics = +10-30us).
// R11 A/B: explicit staging == compiler scheduling (27.4us both).
// THIS ROUND's single variable: occupancy. KITERS 10->5, NBLOCKS 2048->4096,
// __launch_bounds__(256,8) caps VGPR at 64 -> 8 waves/SIMD (was ~4 at >64 VGPR).
// Staged footprint: 5*f32x4 + 5*int + 5*float = 30 VGPR + working set ~= 60.

#define NCLS 80
#define C4   (NCLS / 4)   // 20 float4 per row
#define NBLOCKS 4096
#define NTHREADS 256
#define STRIDE (NBLOCKS * NTHREADS)   // 1,048,576 threads

typedef float f32x4 __attribute__((ext_vector_type(4)));

// ln(1+x) on [0,1], Abramowitz & Stegun 4.1.44 (|eps| <= 3e-8); sum(a_i)=ln2 exactly.
__device__ __forceinline__ float log1p_poly(float x) {
    float p = -0.0064535442f;
    p = __builtin_fmaf(p, x,  0.0360884937f);
    p = __builtin_fmaf(p, x, -0.0953293897f);
    p = __builtin_fmaf(p, x,  0.1676540711f);
    p = __builtin_fmaf(p, x, -0.2407338084f);
    p = __builtin_fmaf(p, x,  0.3317990258f);
    p = __builtin_fmaf(p, x, -0.4998741238f);
    p = __builtin_fmaf(p, x,  0.9999964239f);
    return p * x;
}

__device__ __forceinline__ float elem_term(float x, int c, int t, int wi, bool neg) {
    const bool  pos = (c == t);
    const int   bit = (c < 32) ? ((wi >> c) & 1) : 0;   // schema bit (0 for c>=16 anyway)
    const float m   = neg ? (float)bit : 1.0f;
    const float a   = pos ? 0.25f : 0.75f;
    const float y   = pos ? -x : x;
    const float e   = __expf(-fabsf(x));                 // v_exp_f32, e in (0,1]
    const float inv = __builtin_amdgcn_rcpf(1.0f + e);   // v_rcp_f32
    const float s   = (y >= 0.0f) ? inv : e * inv;       // sigmoid(y)
    const float sp  = fmaxf(y, 0.0f) + log1p_poly(e);    // softplus(y), stable
    return (a * m) * (s * s) * sp;
}

template<int KITERS>
__global__ void __launch_bounds__(NTHREADS, 8)
cfs_main(const float* __restrict__ pred,
         const int*   __restrict__ targets,
         const float* __restrict__ weight,
         float* __restrict__ partials,
         int total4) {
    const int tid = blockIdx.x * NTHREADS + threadIdx.x;

    float acc = 0.0f;
    if constexpr (KITERS > 0) {
        // Stage all loads (statically indexed -> registers, all in flight).
        f32x4 x[KITERS];
        int   tt[KITERS];
        float wf[KITERS];
        #pragma unroll
        for (int k = 0; k < KITERS; ++k) {
            const int i = tid + k * STRIDE;
            const int n = i / C4;
            x[k]  = reinterpret_cast<const f32x4*>(pred)[i];
            tt[k] = targets[n];
            wf[k] = weight[n];
        }
        #pragma unroll
        for (int k = 0; k < KITERS; ++k) {
            const int i  = tid + k * STRIDE;
            const int n  = i / C4;              // magic-mul divide by 20
            const int c0 = (i - n * C4) * 4;
            const int   t   = tt[k];
            const float w   = wf[k];
            const int   wi  = (int)w;
            const bool  neg = (t == NCLS);
            const float rw  = (w > 0.0f) ? 1.0f : 0.0f;
            const float s4 = elem_term(x[k][0], c0 + 0, t, wi, neg)
                           + elem_term(x[k][1], c0 + 1, t, wi, neg)
                           + elem_term(x[k][2], c0 + 2, t, wi, neg)
                           + elem_term(x[k][3], c0 + 3, t, wi, neg);
            acc = __builtin_fmaf(rw, s4, acc);
        }
    } else {
        for (int i = tid; i < total4; i += STRIDE) {
            const int n  = i / C4;
            const int c0 = (i - n * C4) * 4;
            const f32x4 x4 = reinterpret_cast<const f32x4*>(pred)[i];
            const int   t   = targets[n];
            const float w   = weight[n];
            const int   wi  = (int)w;
            const bool  neg = (t == NCLS);
            const float rw  = (w > 0.0f) ? 1.0f : 0.0f;
            const float s4 = elem_term(x4[0], c0 + 0, t, wi, neg)
                           + elem_term(x4[1], c0 + 1, t, wi, neg)
                           + elem_term(x4[2], c0 + 2, t, wi, neg)
                           + elem_term(x4[3], c0 + 3, t, wi, neg);
            acc = __builtin_fmaf(rw, s4, acc);
        }
    }

    // wave (64-lane) reduction
    #pragma unroll
    for (int off = 32; off > 0; off >>= 1)
        acc += __shfl_down(acc, off, 64);

    __shared__ float smem[NTHREADS / 64];
    const int lane = threadIdx.x & 63;
    const int wid  = threadIdx.x >> 6;
    if (lane == 0) smem[wid] = acc;
    __syncthreads();
    if (threadIdx.x == 0)
        partials[blockIdx.x] = smem[0] + smem[1] + smem[2] + smem[3];
}

__global__ void __launch_bounds__(NTHREADS)
cfs_reduce(const float* __restrict__ partials, float* __restrict__ out,
           int nparts4, float scale) {
    // nparts4 = NBLOCKS/4 float4 elements; fixed-order -> deterministic
    float acc = 0.0f;
    for (int i = threadIdx.x; i < nparts4; i += NTHREADS) {
        const f32x4 p4 = reinterpret_cast<const f32x4*>(partials)[i];
        acc += (p4[0] + p4[1]) + (p4[2] + p4[3]);
    }
    #pragma unroll
    for (int off = 32; off > 0; off >>= 1)
        acc += __shfl_down(acc, off, 64);

    __shared__ float smem[NTHREADS / 64];
    const int lane = threadIdx.x & 63;
    const int wid  = threadIdx.x >> 6;
    if (lane == 0) smem[wid] = acc;
    __syncthreads();
    if (threadIdx.x == 0)
        out[0] = (smem[0] + smem[1] + smem[2] + smem[3]) * scale;
}

extern "C" void kernel_launch(void* const* d_in, const int* in_sizes, int n_in,
                              void* d_out, int out_size, void* d_ws, size_t ws_size,
                              hipStream_t stream) {
    const float* pred     = (const float*)d_in[0];
    const int*   targets  = (const int*)  d_in[1];
    const float* weight   = (const float*)d_in[2];
    float*       out      = (float*)d_out;
    float*       partials = (float*)d_ws;   // NBLOCKS floats of scratch

    const int n_rows = in_sizes[1];          // 262144
    const int total4 = n_rows * C4;          // 5,242,880
    const float inv_total = 1.0f / (float)(n_rows * NCLS);

    if (total4 == 5 * STRIDE) {
        cfs_main<5><<<NBLOCKS, NTHREADS, 0, stream>>>(pred, targets, weight, partials, total4);
    } else {
        cfs_main<0><<<NBLOCKS, NTHREADS, 0, stream>>>(pred, targets, weight, partials, total4);
    }
    cfs_reduce<<<1, NTHREADS, 0, stream>>>(partials, out, NBLOCKS / 4, inv_total);
}

// Round 14
// 26.389 us; speedup vs baseline: 4.1035x; 1.0039x over previous
//
#include <hip/hip_runtime.h>
#include <hip/hip_bf16.h>

// CrossSigmoidFocalLoss: mean over (N,C) of focal_w * bce * row_w * cross_mask
// Per element, with p = sigmoid(x):
//   c==t (positive): 0.25 * sigmoid(-x)^2 * softplus(-x)
//   c!=t (negative): 0.75 * sigmoid(x)^2  * softplus(x)   [* schema bit if t==C]
// Shared-subexpression form (one exp, one rcp, one log per element):
//   e = exp(-|x|); d = 1+e; r = 1/d; sigmoid(x) = x>=0 ? r : e*r;
//   sigmoid(-x) = the other select; softplus(x) = max(x,0)+ln(d);
//   softplus(-x) = softplus(x) - x.
// weight < 2^16 so schema bits for c>=16 are 0 (c0>=32 shift guarded).
//
// Ledger: R8 __threadfence/block = +66us. R9 same-addr arrival atomics = +10-30us.
// R11 staging neutral. R12 occupancy neutral. R1->R4->R5 VALU cuts = all wins.
// THIS ROUND: ~30% VALU cut (dual-orientation algebra + v_log softplus + hoisted
// index math via STRIDE % 20 == 0).

#define NCLS 80
#define C4   (NCLS / 4)              // 20 float4 per row
#define NBLOCKS 2560                 // multiple of 5 -> STRIDE % 20 == 0
#define NTHREADS 256
#define KIT 8
#define STRIDE (NBLOCKS * NTHREADS)  // 655,360 threads
#define ROWSTEP (STRIDE / C4)        // 32,768 rows per k-step

typedef float f32x4 __attribute__((ext_vector_type(4)));

__device__ __forceinline__ float quad_term(f32x4 x4, int t, float w, int c0) {
    const int   wi  = (int)w;
    const bool  neg = (t == NCLS);
    const float qn  = (w > 0.0f) ? 0.75f : 0.0f;
    const float qp  = (w > 0.0f) ? 0.25f : 0.0f;
    const int   wsh   = (c0 < 32) ? (wi >> c0) : 0;   // guard shift >= 32 (UB)
    const int   maskA = neg ? (wsh & 15) : 15;        // neg rows: schema bits; pos rows: all
    float acc = 0.0f;
    #pragma unroll
    for (int j = 0; j < 4; ++j) {
        const float x   = x4[j];
        const float e   = __expf(-fabsf(x));            // v_mul(-|x|*log2e) + v_exp
        const float d   = 1.0f + e;
        const float r   = __builtin_amdgcn_rcpf(d);     // v_rcp
        const float sB  = e * r;
        const bool  f   = (x >= 0.0f);
        const float s   = f ? r : sB;                   // sigmoid(x)
        const float s1  = f ? sB : r;                   // sigmoid(-x)
        const float lg  = __log2f(d);                   // v_log
        const float sp  = __builtin_fmaf(lg, 0.69314718055994531f, fmaxf(x, 0.0f)); // softplus(x)
        const float sp1 = sp - x;                       // softplus(-x)
        const float g   = (s * s) * sp;
        const float g1  = (s1 * s1) * sp1;
        const float cN  = ((maskA >> j) & 1) ? qn : 0.0f;
        const bool  ist = ((c0 + j) == t);              // never true on neg rows (t==80)
        acc += ist ? (qp * g1) : (cN * g);
    }
    return acc;
}

template<int KITERS>
__global__ void __launch_bounds__(NTHREADS)
cfs_main(const float* __restrict__ pred,
         const int*   __restrict__ targets,
         const float* __restrict__ weight,
         float* __restrict__ partials,
         int total4) {
    const int tid = blockIdx.x * NTHREADS + threadIdx.x;

    float acc = 0.0f;
    if constexpr (KITERS > 0) {
        const int n0 = tid / C4;                  // one magic-divide, hoisted
        const int c0 = (tid - n0 * C4) * 4;       // constant across k
        #pragma unroll
        for (int k = 0; k < KITERS; ++k) {
            const int i = tid + k * STRIDE;
            const int n = n0 + k * ROWSTEP;       // 1 add per k
            const f32x4 x4 = reinterpret_cast<const f32x4*>(pred)[i];
            acc += quad_term(x4, targets[n], weight[n], c0);
        }
    } else {
        for (int i = tid; i < total4; i += STRIDE) {
            const int n  = i / C4;
            const int c0 = (i - n * C4) * 4;
            const f32x4 x4 = reinterpret_cast<const f32x4*>(pred)[i];
            acc += quad_term(x4, targets[n], weight[n], c0);
        }
    }

    // wave (64-lane) reduction
    #pragma unroll
    for (int off = 32; off > 0; off >>= 1)
        acc += __shfl_down(acc, off, 64);

    __shared__ float smem[NTHREADS / 64];
    const int lane = threadIdx.x & 63;
    const int wid  = threadIdx.x >> 6;
    if (lane == 0) smem[wid] = acc;
    __syncthreads();
    if (threadIdx.x == 0)
        partials[blockIdx.x] = smem[0] + smem[1] + smem[2] + smem[3];
}

__global__ void __launch_bounds__(NTHREADS)
cfs_reduce(const float* __restrict__ partials, float* __restrict__ out,
           int nparts4, float scale) {
    // nparts4 float4 elements; fixed-order -> deterministic
    float acc = 0.0f;
    for (int i = threadIdx.x; i < nparts4; i += NTHREADS) {
        const f32x4 p4 = reinterpret_cast<const f32x4*>(partials)[i];
        acc += (p4[0] + p4[1]) + (p4[2] + p4[3]);
    }
    #pragma unroll
    for (int off = 32; off > 0; off >>= 1)
        acc += __shfl_down(acc, off, 64);

    __shared__ float smem[NTHREADS / 64];
    const int lane = threadIdx.x & 63;
    const int wid  = threadIdx.x >> 6;
    if (lane == 0) smem[wid] = acc;
    __syncthreads();
    if (threadIdx.x == 0)
        out[0] = (smem[0] + smem[1] + smem[2] + smem[3]) * scale;
}

extern "C" void kernel_launch(void* const* d_in, const int* in_sizes, int n_in,
                              void* d_out, int out_size, void* d_ws, size_t ws_size,
                              hipStream_t stream) {
    const float* pred     = (const float*)d_in[0];
    const int*   targets  = (const int*)  d_in[1];
    const float* weight   = (const float*)d_in[2];
    float*       out      = (float*)d_out;
    float*       partials = (float*)d_ws;   // NBLOCKS floats of scratch

    const int n_rows = in_sizes[1];          // 262144
    const int total4 = n_rows * C4;          // 5,242,880
    const float inv_total = 1.0f / (float)(n_rows * NCLS);

    if (total4 == KIT * STRIDE) {
        cfs_main<KIT><<<NBLOCKS, NTHREADS, 0, stream>>>(pred, targets, weight, partials, total4);
    } else {
        cfs_main<0><<<NBLOCKS, NTHREADS, 0, stream>>>(pred, targets, weight, partials, total4);
    }
    cfs_reduce<<<1, NTHREADS, 0, stream>>>(partials, out, NBLOCKS / 4, inv_total);
}